// Round 1
// baseline (95.144 us; speedup 1.0000x reference)
//
#include <hip/hip_runtime.h>

// QuantumVQCHead, fully fused single kernel:
//   a = h @ W_pre^T  (16384x512 @ 512x8 f32 GEMV, one wave per 2 rows)
//   then per-row epilogue: tanh/clip angle, single-qubit Bloch vectors,
//   Pauli-propagated observables through the CNOT ring, L2-normalize.
// No workspace use at all (d_ws untouched -> no dependency on the harness's
// 268 MB workspace-poison fill).
//
// Observable algebra (verified by stabilizer conjugation through the ring
// C70*C67*...*C01, in that operator order):
//   X[w] = Xw*X{w+1} (w<7),  X[7] = X7*X0*X1
//   Y[0] = X0*Y1*Z2..Z7 ; Y[w] = Yw*X{w+1}*Z0..Z{w-1} (1<=w<=6)
//   Y[7] = -Y7*Y0*Y1*Z2..Z6
//   Z[0] = Z1..Z7 ; Z[w>=1] = Z0..Zw
// with per-qubit Bloch components X,Y,Z of |chi> = RZ RY RX RY(a)|0>.

__global__ __launch_bounds__(256) void vqc_fused(
    const float* __restrict__ h,    // [B,512]
    const float* __restrict__ Wp,   // [8,512]
    const float* __restrict__ bp,   // [8]
    const float* __restrict__ wt,   // [1,8,3]
    float* __restrict__ out,        // [B,24]
    int B)
{
    const int lane = threadIdx.x & 63;
    const int wave = (blockIdx.x * blockDim.x + threadIdx.x) >> 6;

    const int row0 = wave * 2;
    if (row0 >= B) return;
    const int row1 = row0 + 1;

    // lane covers columns [lane*8, lane*8+8)
    const float4* W4 = (const float4*)Wp;
    float wf[8][8];
    #pragma unroll
    for (int q = 0; q < 8; ++q) {
        float4 w0 = W4[q * 128 + lane * 2 + 0];
        float4 w1 = W4[q * 128 + lane * 2 + 1];
        wf[q][0] = w0.x; wf[q][1] = w0.y; wf[q][2] = w0.z; wf[q][3] = w0.w;
        wf[q][4] = w1.x; wf[q][5] = w1.y; wf[q][6] = w1.z; wf[q][7] = w1.w;
    }

    const int b3 = (lane >> 3) & 1, b4 = (lane >> 4) & 1, b5 = (lane >> 5) & 1;
    const float4* H4 = (const float4*)h;

    float4 h00 = H4[row0 * 128 + lane * 2 + 0];
    float4 h01 = H4[row0 * 128 + lane * 2 + 1];
    float4 h10 = H4[(row1 < B ? row1 : row0) * 128 + lane * 2 + 0];
    float4 h11 = H4[(row1 < B ? row1 : row0) * 128 + lane * 2 + 1];

    float hf0[8] = { h00.x, h00.y, h00.z, h00.w, h01.x, h01.y, h01.z, h01.w };
    float hf1[8] = { h10.x, h10.y, h10.z, h10.w, h11.x, h11.y, h11.z, h11.w };

    float acc0[8], acc1[8];
    #pragma unroll
    for (int q = 0; q < 8; ++q) {
        float a0 = 0.f, a1 = 0.f;
        #pragma unroll
        for (int j = 0; j < 8; ++j) {
            a0 = fmaf(wf[q][j], hf0[j], a0);
            a1 = fmaf(wf[q][j], hf1[j], a1);
        }
        acc0[q] = a0; acc1[q] = a1;
    }

    // log-halving reduce: distribute 8 accs over lane bits 3..5
    float n0[4], n1[4];
    #pragma unroll
    for (int j = 0; j < 4; ++j) {
        float k0 = b3 ? acc0[1 + 2*j] : acc0[0 + 2*j];
        float s0 = b3 ? acc0[0 + 2*j] : acc0[1 + 2*j];
        float k1 = b3 ? acc1[1 + 2*j] : acc1[0 + 2*j];
        float s1 = b3 ? acc1[0 + 2*j] : acc1[1 + 2*j];
        n0[j] = k0 + __shfl_xor(s0, 8);
        n1[j] = k1 + __shfl_xor(s1, 8);
    }
    float m0[2], m1[2];
    #pragma unroll
    for (int i = 0; i < 2; ++i) {
        float k0 = b4 ? n0[1 + 2*i] : n0[0 + 2*i];
        float s0 = b4 ? n0[0 + 2*i] : n0[1 + 2*i];
        float k1 = b4 ? n1[1 + 2*i] : n1[0 + 2*i];
        float s1 = b4 ? n1[0 + 2*i] : n1[1 + 2*i];
        m0[i] = k0 + __shfl_xor(s0, 16);
        m1[i] = k1 + __shfl_xor(s1, 16);
    }
    float v0, v1;
    {
        float k0 = b5 ? m0[1] : m0[0];
        float s0 = b5 ? m0[0] : m0[1];
        float k1 = b5 ? m1[1] : m1[0];
        float s1 = b5 ? m1[0] : m1[1];
        v0 = k0 + __shfl_xor(s0, 32);
        v1 = k1 + __shfl_xor(s1, 32);
    }
    // butterfly over bits 0..2: every lane in each 8-lane group now holds the
    // full 512-col sum for qubit q = lane>>3
    v0 += __shfl_xor(v0, 1); v1 += __shfl_xor(v1, 1);
    v0 += __shfl_xor(v0, 2); v1 += __shfl_xor(v1, 2);
    v0 += __shfl_xor(v0, 4); v1 += __shfl_xor(v1, 4);

    // gather the 8 qubit angles into every lane; even lanes take row0,
    // odd lanes take row1 (lane 8q holds v0, lane 8q+1 holds v1 -> bpermute)
    const int r = lane & 1;
    float vsel = r ? v1 : v0;
    float av[8];
    #pragma unroll
    for (int q = 0; q < 8; ++q) av[q] = __shfl(vsel, q * 8 + r);

    // ---- per-row epilogue, computed redundantly across lanes ----
    float X[8], Y[8], Z[8];
    #pragma unroll
    for (int q = 0; q < 8; ++q) {
        // batch-constant single-qubit matrix M = RZ(t2)RY(t1)RX(t0)
        float t0 = wt[q * 3 + 0] * 0.5f;
        float t1 = wt[q * 3 + 1] * 0.5f;
        float t2 = wt[q * 3 + 2] * 0.5f;
        float s0, c0, s1, c1, sz, cz;
        __sincosf(t0, &s0, &c0);
        __sincosf(t1, &s1, &c1);
        __sincosf(t2, &sz, &cz);
        float N00r =  c1 * c0, N00i =  s1 * s0;
        float N01r = -s1 * c0, N01i = -c1 * s0;
        float N10r =  s1 * c0, N10i = -c1 * s0;
        float N11r =  c1 * c0, N11i = -s1 * s0;
        float M00r = cz * N00r + sz * N00i, M00i = cz * N00i - sz * N00r;
        float M01r = cz * N01r + sz * N01i, M01i = cz * N01i - sz * N01r;
        float M10r = cz * N10r - sz * N10i, M10i = cz * N10i + sz * N10r;
        float M11r = cz * N11r - sz * N11i, M11i = cz * N11i + sz * N11r;

        float a = av[q] + bp[q];
        a = fminf(fmaxf(a, -15.f), 15.f);
        float e = __expf(a + a);
        float th = (e - 1.f) / (e + 1.f);          // tanh(a)
        float phi = th * 0.78539816339744831f;     // tanh(a)*(pi/2)/2
        float ss, cc;
        __sincosf(phi, &ss, &cc);
        float ar = M00r * cc + M01r * ss, ai = M00i * cc + M01i * ss;
        float br = M10r * cc + M11r * ss, bi = M10i * cc + M11i * ss;
        Z[q] = (ar * ar + ai * ai) - (br * br + bi * bi);
        X[q] = 2.f * (ar * br + ai * bi);
        Y[q] = 2.f * (ar * bi - ai * br);
    }

    // prefix P[w] = Z0..Zw ; suffix T[w] = Zw..Z7
    float P[8], T[8];
    P[0] = Z[0];
    #pragma unroll
    for (int w = 1; w < 8; ++w) P[w] = P[w - 1] * Z[w];
    T[7] = Z[7];
    #pragma unroll
    for (int w = 6; w >= 0; --w) T[w] = Z[w] * T[w + 1];
    float Z2to6 = Z[2] * Z[3] * Z[4] * Z[5] * Z[6];

    float o[24];
    #pragma unroll
    for (int w = 0; w < 7; ++w) o[3 * w] = X[w] * X[w + 1];
    o[21] = X[7] * X[0] * X[1];
    o[1] = X[0] * Y[1] * T[2];
    #pragma unroll
    for (int w = 1; w < 7; ++w) o[3 * w + 1] = Y[w] * X[w + 1] * P[w - 1];
    o[22] = -Y[7] * Y[0] * Y[1] * Z2to6;
    o[2] = T[1];
    #pragma unroll
    for (int w = 1; w < 8; ++w) o[3 * w + 2] = P[w];

    float sq = 0.f;
    #pragma unroll
    for (int j = 0; j < 24; ++j) sq = fmaf(o[j], o[j], sq);
    float inv = 1.f / fmaxf(sqrtf(sq), 1e-12f);

    if (lane < 2) {
        const int row = row0 + lane;
        if (row < B) {
            float4* O4 = (float4*)(out + row * 24);
            #pragma unroll
            for (int j = 0; j < 6; ++j) {
                float4 vv = { o[4 * j] * inv, o[4 * j + 1] * inv,
                              o[4 * j + 2] * inv, o[4 * j + 3] * inv };
                O4[j] = vv;
            }
        }
    }
}

extern "C" void kernel_launch(void* const* d_in, const int* in_sizes, int n_in,
                              void* d_out, int out_size, void* d_ws, size_t ws_size,
                              hipStream_t stream) {
    const float* h  = (const float*)d_in[0];
    const float* Wp = (const float*)d_in[1];
    const float* bp = (const float*)d_in[2];
    const float* wt = (const float*)d_in[3];
    float* out = (float*)d_out;
    (void)d_ws; (void)ws_size;

    const int B = in_sizes[0] / 512;      // 16384
    // 2 rows per wave, 4 waves per block -> 8 rows per block (no overshoot)
    const int nblk = (B + 7) / 8;         // 2048
    vqc_fused<<<nblk, 256, 0, stream>>>(h, Wp, bp, wt, out, B);
}

// Round 2
// 80.948 us; speedup vs baseline: 1.1754x; 1.1754x over previous
//
#include <hip/hip_runtime.h>

// QuantumVQCHead, single fused kernel, block-local two-phase:
//   Phase 1 (per wave): 16 rows of a = h @ W_pre^T via the 2-row lane-split
//            dot + log-halving butterfly reduce, 8 sequential row-pairs with
//            one-pair prefetch. W (16 KB) loaded into registers ONCE per wave
//            (amortized 8x better than the 2-row/wave version). Dots -> LDS.
//   Phase 2 (wave 0): one row per lane (64 rows/block), scalar epilogue:
//            tanh/clip angle, single-qubit Bloch vectors, Pauli-propagated
//            observables through the CNOT ring, L2-normalize.
// No d_ws use, no second launch, no dead waves. Grid = B/64 = 256 blocks
// (1 block/CU) so register pressure does not cost occupancy.
//
// Observable algebra (verified by stabilizer conjugation through the ring
// C70*C67*...*C01, in that operator order):
//   X[w] = Xw*X{w+1} (w<7),  X[7] = X7*X0*X1
//   Y[0] = X0*Y1*Z2..Z7 ; Y[w] = Yw*X{w+1}*Z0..Z{w-1} (1<=w<=6)
//   Y[7] = -Y7*Y0*Y1*Z2..Z6
//   Z[0] = Z1..Z7 ; Z[w>=1] = Z0..Zw
// with per-qubit Bloch components X,Y,Z of |chi> = RZ RY RX RY(a)|0>.

__global__ __launch_bounds__(256, 1) void vqc_block64(
    const float* __restrict__ h,    // [B,512]
    const float* __restrict__ Wp,   // [8,512]
    const float* __restrict__ bp,   // [8]
    const float* __restrict__ wt,   // [1,8,3]
    float* __restrict__ out,        // [B,24]
    int B)
{
    // pad to 9: lane t reads row t at dword 9t+q -> banks 2-way only (free)
    __shared__ float aw_lds[64][9];

    const int lane = threadIdx.x & 63;
    const int wv   = threadIdx.x >> 6;            // wave in block, 0..3
    const int blockRow = blockIdx.x * 64;
    const int waveRow  = blockRow + wv * 16;      // 16 rows per wave

    const int b3 = (lane >> 3) & 1, b4 = (lane >> 4) & 1, b5 = (lane >> 5) & 1;

    // W fragment: lane covers columns [lane*8, lane*8+8), loaded once
    const float4* W4 = (const float4*)Wp;
    float wf[8][8];
    #pragma unroll
    for (int q = 0; q < 8; ++q) {
        float4 w0 = W4[q * 128 + lane * 2 + 0];
        float4 w1 = W4[q * 128 + lane * 2 + 1];
        wf[q][0] = w0.x; wf[q][1] = w0.y; wf[q][2] = w0.z; wf[q][3] = w0.w;
        wf[q][4] = w1.x; wf[q][5] = w1.y; wf[q][6] = w1.z; wf[q][7] = w1.w;
    }

    const float4* H4 = (const float4*)h;
    const int Bm1 = B - 1;

    if (waveRow < B) {
        // prefetch pair 0
        int r0 = waveRow < Bm1 ? waveRow : Bm1;
        int r1 = waveRow + 1 < Bm1 ? waveRow + 1 : Bm1;
        float4 p00 = H4[r0 * 128 + lane * 2 + 0];
        float4 p01 = H4[r0 * 128 + lane * 2 + 1];
        float4 p10 = H4[r1 * 128 + lane * 2 + 0];
        float4 p11 = H4[r1 * 128 + lane * 2 + 1];

        #pragma unroll
        for (int p = 0; p < 8; ++p) {
            float hf0[8] = { p00.x, p00.y, p00.z, p00.w,
                             p01.x, p01.y, p01.z, p01.w };
            float hf1[8] = { p10.x, p10.y, p10.z, p10.w,
                             p11.x, p11.y, p11.z, p11.w };
            if (p < 7) {   // prefetch next pair while reducing this one
                int n0 = waveRow + 2 * (p + 1);
                int n1 = n0 + 1;
                n0 = n0 < Bm1 ? n0 : Bm1;
                n1 = n1 < Bm1 ? n1 : Bm1;
                p00 = H4[n0 * 128 + lane * 2 + 0];
                p01 = H4[n0 * 128 + lane * 2 + 1];
                p10 = H4[n1 * 128 + lane * 2 + 0];
                p11 = H4[n1 * 128 + lane * 2 + 1];
            }

            float acc0[8], acc1[8];
            #pragma unroll
            for (int q = 0; q < 8; ++q) {
                float a0 = 0.f, a1 = 0.f;
                #pragma unroll
                for (int j = 0; j < 8; ++j) {
                    a0 = fmaf(wf[q][j], hf0[j], a0);
                    a1 = fmaf(wf[q][j], hf1[j], a1);
                }
                acc0[q] = a0; acc1[q] = a1;
            }

            // log-halving reduce over lane bits 3..5, then butterfly 0..2
            float n0v[4], n1v[4];
            #pragma unroll
            for (int j = 0; j < 4; ++j) {
                float k0 = b3 ? acc0[1 + 2*j] : acc0[0 + 2*j];
                float s0 = b3 ? acc0[0 + 2*j] : acc0[1 + 2*j];
                float k1 = b3 ? acc1[1 + 2*j] : acc1[0 + 2*j];
                float s1 = b3 ? acc1[0 + 2*j] : acc1[1 + 2*j];
                n0v[j] = k0 + __shfl_xor(s0, 8);
                n1v[j] = k1 + __shfl_xor(s1, 8);
            }
            float m0v[2], m1v[2];
            #pragma unroll
            for (int i = 0; i < 2; ++i) {
                float k0 = b4 ? n0v[1 + 2*i] : n0v[0 + 2*i];
                float s0 = b4 ? n0v[0 + 2*i] : n0v[1 + 2*i];
                float k1 = b4 ? n1v[1 + 2*i] : n1v[0 + 2*i];
                float s1 = b4 ? n1v[0 + 2*i] : n1v[1 + 2*i];
                m0v[i] = k0 + __shfl_xor(s0, 16);
                m1v[i] = k1 + __shfl_xor(s1, 16);
            }
            float v0, v1;
            {
                float k0 = b5 ? m0v[1] : m0v[0];
                float s0 = b5 ? m0v[0] : m0v[1];
                float k1 = b5 ? m1v[1] : m1v[0];
                float s1 = b5 ? m1v[0] : m1v[1];
                v0 = k0 + __shfl_xor(s0, 32);
                v1 = k1 + __shfl_xor(s1, 32);
            }
            v0 += __shfl_xor(v0, 1); v1 += __shfl_xor(v1, 1);
            v0 += __shfl_xor(v0, 2); v1 += __shfl_xor(v1, 2);
            v0 += __shfl_xor(v0, 4); v1 += __shfl_xor(v1, 4);

            if ((lane & 7) == 0) {
                int q = lane >> 3;
                aw_lds[wv * 16 + 2 * p + 0][q] = v0;
                aw_lds[wv * 16 + 2 * p + 1][q] = v1;
            }
        }
    }

    __syncthreads();

    // ---- Phase 2: wave 0, one row per lane ----
    if (threadIdx.x < 64) {
        const int row = blockRow + (int)threadIdx.x;
        if (row < B) {
            float av[8];
            #pragma unroll
            for (int q = 0; q < 8; ++q) av[q] = aw_lds[threadIdx.x][q];

            float X[8], Y[8], Z[8];
            #pragma unroll
            for (int q = 0; q < 8; ++q) {
                // batch-constant single-qubit matrix M = RZ(t2)RY(t1)RX(t0)
                float t0 = wt[q * 3 + 0] * 0.5f;
                float t1 = wt[q * 3 + 1] * 0.5f;
                float t2 = wt[q * 3 + 2] * 0.5f;
                float s0, c0, s1, c1, sz, cz;
                __sincosf(t0, &s0, &c0);
                __sincosf(t1, &s1, &c1);
                __sincosf(t2, &sz, &cz);
                float N00r =  c1 * c0, N00i =  s1 * s0;
                float N01r = -s1 * c0, N01i = -c1 * s0;
                float N10r =  s1 * c0, N10i = -c1 * s0;
                float N11r =  c1 * c0, N11i = -s1 * s0;
                float M00r = cz * N00r + sz * N00i, M00i = cz * N00i - sz * N00r;
                float M01r = cz * N01r + sz * N01i, M01i = cz * N01i - sz * N01r;
                float M10r = cz * N10r - sz * N10i, M10i = cz * N10i + sz * N10r;
                float M11r = cz * N11r - sz * N11i, M11i = cz * N11i + sz * N11r;

                float a = av[q] + bp[q];
                a = fminf(fmaxf(a, -15.f), 15.f);
                float e = __expf(a + a);
                float th = (e - 1.f) / (e + 1.f);          // tanh(a)
                float phi = th * 0.78539816339744831f;     // tanh(a)*(pi/2)/2
                float ss, cc;
                __sincosf(phi, &ss, &cc);
                float ar = M00r * cc + M01r * ss, ai = M00i * cc + M01i * ss;
                float br = M10r * cc + M11r * ss, bi = M10i * cc + M11i * ss;
                Z[q] = (ar * ar + ai * ai) - (br * br + bi * bi);
                X[q] = 2.f * (ar * br + ai * bi);
                Y[q] = 2.f * (ar * bi - ai * br);
            }

            // prefix P[w] = Z0..Zw ; suffix T[w] = Zw..Z7
            float P[8], T[8];
            P[0] = Z[0];
            #pragma unroll
            for (int w = 1; w < 8; ++w) P[w] = P[w - 1] * Z[w];
            T[7] = Z[7];
            #pragma unroll
            for (int w = 6; w >= 0; --w) T[w] = Z[w] * T[w + 1];
            float Z2to6 = Z[2] * Z[3] * Z[4] * Z[5] * Z[6];

            float o[24];
            #pragma unroll
            for (int w = 0; w < 7; ++w) o[3 * w] = X[w] * X[w + 1];
            o[21] = X[7] * X[0] * X[1];
            o[1] = X[0] * Y[1] * T[2];
            #pragma unroll
            for (int w = 1; w < 7; ++w) o[3 * w + 1] = Y[w] * X[w + 1] * P[w - 1];
            o[22] = -Y[7] * Y[0] * Y[1] * Z2to6;
            o[2] = T[1];
            #pragma unroll
            for (int w = 1; w < 8; ++w) o[3 * w + 2] = P[w];

            float sq = 0.f;
            #pragma unroll
            for (int j = 0; j < 24; ++j) sq = fmaf(o[j], o[j], sq);
            float inv = 1.f / fmaxf(sqrtf(sq), 1e-12f);

            float4* O4 = (float4*)(out + row * 24);
            #pragma unroll
            for (int j = 0; j < 6; ++j) {
                float4 vv = { o[4 * j] * inv, o[4 * j + 1] * inv,
                              o[4 * j + 2] * inv, o[4 * j + 3] * inv };
                O4[j] = vv;
            }
        }
    }
}

extern "C" void kernel_launch(void* const* d_in, const int* in_sizes, int n_in,
                              void* d_out, int out_size, void* d_ws, size_t ws_size,
                              hipStream_t stream) {
    const float* h  = (const float*)d_in[0];
    const float* Wp = (const float*)d_in[1];
    const float* bp = (const float*)d_in[2];
    const float* wt = (const float*)d_in[3];
    float* out = (float*)d_out;
    (void)d_ws; (void)ws_size;

    const int B = in_sizes[0] / 512;          // 16384
    const int nblk = (B + 63) / 64;           // 256 blocks, 64 rows each
    vqc_block64<<<nblk, 256, 0, stream>>>(h, Wp, bp, wt, out, B);
}